// Round 11
// baseline (50713.901 us; speedup 1.0000x reference)
//
#include <hip/hip_runtime.h>
#include <math.h>

// LSTM B=128,T=1024,D=64,H=256,C=6 — R11: 512-thr / 8-wave / 2 waves per SIMD.
//
// R10 left 2.4us/step of latency exposure at 1 wave/SIMD (VALUBusy 23%).
// R11 adds TLP while staying inside LLVM's hard 128-V allocation for 512-thr
// blocks (R4-R7 evidence): per-thread = 2 cols x {32 pairs named-V (64 regs),
// 64 pairs AGPR via asm (128 regs), 32 pairs LDS b128}. V 64+working<=128,
// A=128; per-wave 256, x2 waves = full 512-reg SIMD pool.
// Gate split (R6, proven): tid<256 owns {i,g} of unit u=tid&255, else {f,o};
// f,o published via LDS; 2 barriers/step; h double-buffered f16;
// projection: wave w (0..5) -> class w. xg precompute unchanged (R6-R10).

#define Tt 1024
#define Dd 64
#define Hh 256
#define G4 1024
#define Cc 6
#define BT (128 * 1024)
#define XG_BYTES ((size_t)BT * G4 * 2)   // 256 MB f16

typedef _Float16 f16x2 __attribute__((ext_vector_type(2)));

__device__ __forceinline__ float dot2(f16x2 a, f16x2 b, float c) {
#if __has_builtin(__builtin_amdgcn_fdot2)
    return __builtin_amdgcn_fdot2(a, b, c, false);
#else
    return c + (float)a.x * (float)b.x + (float)a.y * (float)b.y;
#endif
}
__device__ __forceinline__ float sigm(float p) { return 1.0f / (1.0f + __expf(-p)); }
__device__ __forceinline__ float tanh_fast(float p) {
    return 1.0f - 2.0f / (__expf(2.0f * p) + 1.0f);
}
__device__ __forceinline__ unsigned short f2h(float v) {
    _Float16 h = (_Float16)v;
    return __builtin_bit_cast(unsigned short, h);
}
__device__ __forceinline__ float h2f(unsigned short u) {
    return (float)__builtin_bit_cast(_Float16, u);
}
__device__ __forceinline__ f16x2 bcf(float v) { return __builtin_bit_cast(f16x2, v); }
__device__ __forceinline__ f16x2 bcu(unsigned int v) { return __builtin_bit_cast(f16x2, v); }
__device__ __forceinline__ unsigned int packh(float a, float b) {
    return (unsigned int)f2h(a) | ((unsigned int)f2h(b) << 16);
}

// ---------------- stage 1: xg = x @ Wx + bias, f16 (verified R6-R10) -------
__global__ __launch_bounds__(256) void xg_gemm(
    const float* __restrict__ x, const float* __restrict__ Wx,
    const float* __restrict__ bias, unsigned short* __restrict__ xg)
{
    __shared__ float xs[32][65];
    __shared__ float wsl[64][256];

    const int tid = threadIdx.x;
    const long r0 = (long)blockIdx.x * 32;
    const int  c0 = blockIdx.y * 256;

    {
        const float4* src = (const float4*)(x + r0 * Dd);
        float4 v0 = src[tid], v1 = src[tid + 256];
        int e = tid * 4;
        xs[e >> 6][e & 63] = v0.x; xs[e >> 6][(e & 63) + 1] = v0.y;
        xs[e >> 6][(e & 63) + 2] = v0.z; xs[e >> 6][(e & 63) + 3] = v0.w;
        e += 1024;
        xs[e >> 6][e & 63] = v1.x; xs[e >> 6][(e & 63) + 1] = v1.y;
        xs[e >> 6][(e & 63) + 2] = v1.z; xs[e >> 6][(e & 63) + 3] = v1.w;
    }
    for (int i = tid; i < 64 * 64; i += 256) {
        int d = i >> 6, cq = i & 63;
        *(float4*)&wsl[d][cq * 4] = *(const float4*)(Wx + (long)d * G4 + c0 + cq * 4);
    }
    __syncthreads();

    const int r = tid & 31, cg = tid >> 5;
    float acc[32];
    #pragma unroll
    for (int c = 0; c < 32; ++c) acc[c] = bias[c0 + cg * 32 + c];
    for (int k = 0; k < 64; ++k) {
        float xv = xs[r][k];
        #pragma unroll
        for (int c = 0; c < 32; ++c) acc[c] += xv * wsl[k][cg * 32 + c];
    }
    unsigned int ow[16];
    #pragma unroll
    for (int c2 = 0; c2 < 16; ++c2)
        ow[c2] = packh(acc[2 * c2], acc[2 * c2 + 1]);
    uint4* dst = (uint4*)(xg + (r0 + r) * G4 + c0 + cg * 32);
    dst[0] = make_uint4(ow[0], ow[1], ow[2], ow[3]);
    dst[1] = make_uint4(ow[4], ow[5], ow[6], ow[7]);
    dst[2] = make_uint4(ow[8], ow[9], ow[10], ow[11]);
    dst[3] = make_uint4(ow[12], ow[13], ow[14], ow[15]);
}

// ---------------- stage 2: recurrence (512 thr, 2 cols/thread) -------------
// pair i covers k = 2i,2i+1. col c0 = tid ({i|f} gate), c1 = tid+512 ({g|o}).

#define WLOADV2(i) \
  const f16x2 w0_##i = f16x2{(_Float16)Wh[(2*(i))*G4 + c0], (_Float16)Wh[(2*(i)+1)*G4 + c0]}; \
  const f16x2 w1_##i = f16x2{(_Float16)Wh[(2*(i))*G4 + c1], (_Float16)Wh[(2*(i)+1)*G4 + c1]};

#define AW1(dst, cix, i) { \
    f16x2 t_ = f16x2{(_Float16)Wh[(2*(i))*G4 + (cix)], (_Float16)Wh[(2*(i)+1)*G4 + (cix)]}; \
    asm volatile("v_accvgpr_write_b32 %0, %1" : "=a"(dst) : "v"(__builtin_bit_cast(float, t_))); }

#define WLOADA2(i) \
  float aw0_##i, aw1_##i; \
  AW1(aw0_##i, c0, i) AW1(aw1_##i, c1, i)

#define REPV32(M) \
  M(0) M(1) M(2) M(3) M(4) M(5) M(6) M(7) \
  M(8) M(9) M(10) M(11) M(12) M(13) M(14) M(15) \
  M(16) M(17) M(18) M(19) M(20) M(21) M(22) M(23) \
  M(24) M(25) M(26) M(27) M(28) M(29) M(30) M(31)

#define REPA64(M) \
  M(32) M(33) M(34) M(35) M(36) M(37) M(38) M(39) \
  M(40) M(41) M(42) M(43) M(44) M(45) M(46) M(47) \
  M(48) M(49) M(50) M(51) M(52) M(53) M(54) M(55) \
  M(56) M(57) M(58) M(59) M(60) M(61) M(62) M(63) \
  M(64) M(65) M(66) M(67) M(68) M(69) M(70) M(71) \
  M(72) M(73) M(74) M(75) M(76) M(77) M(78) M(79) \
  M(80) M(81) M(82) M(83) M(84) M(85) M(86) M(87) \
  M(88) M(89) M(90) M(91) M(92) M(93) M(94) M(95)

#define DOTPV(i, hh) { f16x2 h_ = (hh); \
    a0 = dot2(h_, w0_##i, a0); a1 = dot2(h_, w1_##i, a1); }

#define DOTPA(i, hh) { f16x2 h_ = (hh); float t0_, t1_; \
    asm volatile("v_accvgpr_read_b32 %0, %1" : "=v"(t0_) : "a"(aw0_##i)); \
    asm volatile("v_accvgpr_read_b32 %0, %1" : "=v"(t1_) : "a"(aw1_##i)); \
    a0 = dot2(h_, bcf(t0_), a0); a1 = dot2(h_, bcf(t1_), a1); }

#define DOTG4V(g, i0,i1,i2,i3) { float4 hC_ = hvf4[g]; \
    DOTPV(i0, bcf(hC_.x)) DOTPV(i1, bcf(hC_.y)) \
    DOTPV(i2, bcf(hC_.z)) DOTPV(i3, bcf(hC_.w)) }

#define DOTG4A(g, i0,i1,i2,i3) { float4 hC_ = hvf4[g]; \
    DOTPA(i0, bcf(hC_.x)) DOTPA(i1, bcf(hC_.y)) \
    DOTPA(i2, bcf(hC_.z)) DOTPA(i3, bcf(hC_.w)) }

__global__ __launch_bounds__(512, 2) void lstm_xg(
    const unsigned short* __restrict__ xg,  // [B,T,1024] f16, bias folded
    const float* __restrict__ Wh,           // [H,4H]
    const float* __restrict__ Wout,         // [H,C]
    const float* __restrict__ bout,         // [C]
    float* __restrict__ out)                // [B,T,C]
{
    __shared__ alignas(16) unsigned short h_buf[2][Hh];  // double-buffered h
    __shared__ float gl[2][Hh];        // f,o published by hi threads
    __shared__ uint4 wl4[8][G4];       // tail pairs 96..127, 128 KB
    __shared__ float wout_t[Cc][Hh];
    __shared__ float bout_l[8];

    const int tid = threadIdx.x;
    const int b   = blockIdx.x;
    const int c0  = tid;           // gate i (tid<256) or f
    const int c1  = tid + 512;     // gate g (tid<256) or o
    const bool lo = tid < 256;     // wave-uniform (waves 0-3 lo, 4-7 hi)
    const int u   = tid & 255;

    // ---- prologue: 64 named V + 128 AGPR + packed LDS tail ----
    REPV32(WLOADV2)
    REPA64(WLOADA2)

    #pragma unroll
    for (int jq = 0; jq < 8; ++jq) {   // pairs 96+4jq.. : k rows 192+8jq..+7
        const int kb = 192 + 8 * jq;
        wl4[jq][c0] = make_uint4(
            packh(Wh[(kb+0)*G4 + c0], Wh[(kb+1)*G4 + c0]),
            packh(Wh[(kb+2)*G4 + c0], Wh[(kb+3)*G4 + c0]),
            packh(Wh[(kb+4)*G4 + c0], Wh[(kb+5)*G4 + c0]),
            packh(Wh[(kb+6)*G4 + c0], Wh[(kb+7)*G4 + c0]));
        wl4[jq][c1] = make_uint4(
            packh(Wh[(kb+0)*G4 + c1], Wh[(kb+1)*G4 + c1]),
            packh(Wh[(kb+2)*G4 + c1], Wh[(kb+3)*G4 + c1]),
            packh(Wh[(kb+4)*G4 + c1], Wh[(kb+5)*G4 + c1]),
            packh(Wh[(kb+6)*G4 + c1], Wh[(kb+7)*G4 + c1]));
    }
    if (tid < Hh) h_buf[0][tid] = 0;
    for (int i = tid; i < Cc * Hh; i += 512) wout_t[i % Cc][i / Cc] = Wout[i];
    if (tid < Cc) bout_l[tid] = bout[tid];

    const unsigned short* xgB = xg + (long)b * Tt * G4;
    unsigned short xg0 = xgB[c0], xg1 = xgB[c1];   // t = 0
    float c_state = 0.0f;
    int par = 0;
    __syncthreads();

    // ---- time loop (2 barriers/step) ----
    for (int t = 0; t < Tt; ++t) {
        // prefetch next xg (hidden under dots)
        unsigned short n0 = 0, n1 = 0;
        if (t + 1 < Tt) {
            const unsigned short* xn = xgB + (long)(t + 1) * G4;
            n0 = xn[c0]; n1 = xn[c1];
        }

        const float4* hvf4 = (const float4*)h_buf[par];  // h(t-1)
        float a0 = 0.f, a1 = 0.f;
        // pairs 0..31 from VGPRs
        DOTG4V(0,   0, 1, 2, 3)   DOTG4V(1,   4, 5, 6, 7)
        DOTG4V(2,   8, 9,10,11)   DOTG4V(3,  12,13,14,15)
        DOTG4V(4,  16,17,18,19)   DOTG4V(5,  20,21,22,23)
        DOTG4V(6,  24,25,26,27)   DOTG4V(7,  28,29,30,31)
        // pairs 32..95 from AGPRs
        DOTG4A(8,  32,33,34,35)   DOTG4A(9,  36,37,38,39)
        DOTG4A(10, 40,41,42,43)   DOTG4A(11, 44,45,46,47)
        DOTG4A(12, 48,49,50,51)   DOTG4A(13, 52,53,54,55)
        DOTG4A(14, 56,57,58,59)   DOTG4A(15, 60,61,62,63)
        DOTG4A(16, 64,65,66,67)   DOTG4A(17, 68,69,70,71)
        DOTG4A(18, 72,73,74,75)   DOTG4A(19, 76,77,78,79)
        DOTG4A(20, 80,81,82,83)   DOTG4A(21, 84,85,86,87)
        DOTG4A(22, 88,89,90,91)   DOTG4A(23, 92,93,94,95)
        // pairs 96..127 from LDS (b128, conflict-free: lanes consecutive)
        #pragma unroll
        for (int jq = 0; jq < 8; ++jq) {
            float4 hc = hvf4[24 + jq];
            uint4 w0 = wl4[jq][c0];
            uint4 w1 = wl4[jq][c1];
            f16x2 h0 = bcf(hc.x), h1 = bcf(hc.y), h2 = bcf(hc.z), h3 = bcf(hc.w);
            a0 = dot2(h0, bcu(w0.x), a0); a0 = dot2(h1, bcu(w0.y), a0);
            a0 = dot2(h2, bcu(w0.z), a0); a0 = dot2(h3, bcu(w0.w), a0);
            a1 = dot2(h0, bcu(w1.x), a1); a1 = dot2(h1, bcu(w1.y), a1);
            a1 = dot2(h2, bcu(w1.z), a1); a1 = dot2(h3, bcu(w1.w), a1);
        }

        float pre0 = h2f(xg0) + a0;
        float pre1 = h2f(xg1) + a1;
        float r0a, r1a;
        if (lo) { r0a = sigm(pre0); r1a = tanh_fast(pre1); }  // i, g
        else    { r0a = sigm(pre0); r1a = sigm(pre1); }       // f, o

        if (!lo) { gl[0][u] = r0a; gl[1][u] = r1a; }          // publish f, o
        __syncthreads();  // B1: gates visible; all h(t-1) reads done

        if (lo) {
            float fv = gl[0][u], ov = gl[1][u];
            c_state = fv * c_state + r0a * r1a;               // f*c + i*g
            float hval = ov * tanh_fast(c_state);
            h_buf[par ^ 1][u] = f2h(hval);
        }
        __syncthreads();  // B2: h(t) staged

        // fused output projection: wave w -> class w (6 of 8 waves)
        const unsigned short* hn = h_buf[par ^ 1];
        const int w = tid >> 6, l = tid & 63;
        if (w < Cc) {
            float p = 0.0f;
            #pragma unroll
            for (int j = 0; j < 4; ++j)
                p += h2f(hn[l + 64 * j]) * wout_t[w][l + 64 * j];
            #pragma unroll
            for (int off = 32; off > 0; off >>= 1) p += __shfl_down(p, off);
            if (l == 0) out[((long)b * Tt + t) * Cc + w] = p + bout_l[w];
        }

        xg0 = n0; xg1 = n1;
        par ^= 1;
    }
}

// ---------------- fallback: R2 single-block kernel (no ws needed) ----------
__global__ __launch_bounds__(1024) void lstm_fused(
    const float* __restrict__ x, const float* __restrict__ Wx,
    const float* __restrict__ Wh, const float* __restrict__ bias,
    const float* __restrict__ Wout, const float* __restrict__ bout,
    float* __restrict__ out)
{
    __shared__ float h_lds[Hh];
    __shared__ float gates_lds[G4];
    __shared__ float x_lds[2][Dd];
    __shared__ float wout_t[Cc][Hh];
    __shared__ float bout_l[Cc];
    const int tid = threadIdx.x;
    const int b   = blockIdx.x;
    float wx[Dd];
    #pragma unroll
    for (int d = 0; d < Dd; ++d) wx[d] = Wx[d * G4 + tid];
    const float bj = bias[tid];
    if (tid < Hh) h_lds[tid] = 0.0f;
    for (int i = tid; i < Cc * Hh; i += 1024) wout_t[i % Cc][i / Cc] = Wout[i];
    if (tid < Cc) bout_l[tid] = bout[tid];
    const float* xB = x + (long)b * Tt * Dd;
    if (tid < Dd) x_lds[0][tid] = xB[tid];
    float c_state = 0.0f;
    __syncthreads();
    const float* WhB = Wh + tid;
    for (int t = 0; t < Tt; ++t) {
        float gg = bj;
        const float* xr = x_lds[t & 1];
        #pragma unroll
        for (int d = 0; d < Dd; ++d) gg += xr[d] * wx[d];
        #pragma unroll 8
        for (int k = 0; k < Hh; ++k) gg += h_lds[k] * WhB[k * G4];
        float a;
        if (tid < 2 * Hh)      a = 1.0f / (1.0f + expf(-gg));
        else if (tid < 3 * Hh) a = tanhf(gg);
        else                   a = 1.0f / (1.0f + expf(-gg));
        gates_lds[tid] = a;
        __syncthreads();
        if (tid < Hh) {
            float iv = gates_lds[tid], fv = gates_lds[tid + Hh];
            float gv = gates_lds[tid + 2 * Hh], ov = gates_lds[tid + 3 * Hh];
            c_state = fv * c_state + iv * gv;
            h_lds[tid] = ov * tanhf(c_state);
        } else if (tid >= 384 && tid < 448) {
            int tn = t + 1;
            if (tn < Tt) x_lds[tn & 1][tid - 384] = xB[(long)tn * Dd + (tid - 384)];
        }
        __syncthreads();
        const int w = tid >> 6, l = tid & 63;
        if (w < Cc) {
            float p = 0.0f;
            #pragma unroll
            for (int qq = 0; qq < 4; ++qq) p += h_lds[l + 64 * qq] * wout_t[w][l + 64 * qq];
            #pragma unroll
            for (int off = 32; off > 0; off >>= 1) p += __shfl_down(p, off);
            if (l == 0) out[((long)b * Tt + t) * Cc + w] = p + bout_l[w];
        }
    }
}

extern "C" void kernel_launch(void* const* d_in, const int* in_sizes, int n_in,
                              void* d_out, int out_size, void* d_ws, size_t ws_size,
                              hipStream_t stream) {
    const float* x    = (const float*)d_in[0];
    const float* Wx   = (const float*)d_in[1];
    const float* Wh   = (const float*)d_in[2];
    const float* bvec = (const float*)d_in[3];
    const float* Wout = (const float*)d_in[4];
    const float* bout = (const float*)d_in[5];
    float* outp = (float*)d_out;

    if (ws_size >= XG_BYTES) {
        unsigned short* xgws = (unsigned short*)d_ws;
        xg_gemm<<<dim3(BT / 32, 4), dim3(256), 0, stream>>>(x, Wx, bvec, xgws);
        lstm_xg<<<dim3(128), dim3(512), 0, stream>>>(xgws, Wh, Wout, bout, outp);
    } else {
        lstm_fused<<<dim3(128), dim3(1024), 0, stream>>>(x, Wx, Wh, bvec, Wout, bout, outp);
    }
}

// Round 14
// 3311.757 us; speedup vs baseline: 15.3133x; 15.3133x over previous
//
#include <hip/hip_runtime.h>
#include <math.h>

// LSTM B=128,T=1024,D=64,H=256,C=6 — R14: R10 base + explicit SW pipeline.
//
// ISA fact (R13): v_dot2_f32_f16 cannot source AGPRs; only MFMA reads AGPRs
// directly. So weights in AGPR must round-trip via v_accvgpr_read (R10 path).
// R10 = 3.3us/step @ 0.77us issue -> ~2.5us latency exposure. R14 hides it:
//  * 4 rotating h-slot float4 regs: every LDS h read issued ~4 groups (~160cy)
//    ahead of use (LDS latency ~120cy)
//  * AGPR-read double-buffer: group k+1's 16 v_accvgpr_read issued before
//    group k's dots (volatile asm pins placement)
//  * tail-weight uint4 double-buffer (2-group lead)
// Register audit: 128 wV + 16 hs + 32 qbank + 32 tw + ~30 work ~= 240 < 256.
// Numerics identical to R8-R10 (f16 weights/h/xg, fp32 accum): absmax 3.9e-3.

#define Tt 1024
#define Dd 64
#define Hh 256
#define G4 1024
#define Cc 6
#define BT (128 * 1024)
#define XG_BYTES ((size_t)BT * G4 * 2)   // 256 MB f16

typedef _Float16 f16x2 __attribute__((ext_vector_type(2)));

__device__ __forceinline__ float dot2(f16x2 a, f16x2 b, float c) {
#if __has_builtin(__builtin_amdgcn_fdot2)
    return __builtin_amdgcn_fdot2(a, b, c, false);
#else
    return c + (float)a.x * (float)b.x + (float)a.y * (float)b.y;
#endif
}
__device__ __forceinline__ float sigm(float p) { return 1.0f / (1.0f + __expf(-p)); }
__device__ __forceinline__ float tanh_fast(float p) {
    return 1.0f - 2.0f / (__expf(2.0f * p) + 1.0f);
}
__device__ __forceinline__ unsigned short f2h(float v) {
    _Float16 h = (_Float16)v;
    return __builtin_bit_cast(unsigned short, h);
}
__device__ __forceinline__ float h2f(unsigned short u) {
    return (float)__builtin_bit_cast(_Float16, u);
}
__device__ __forceinline__ f16x2 bcf(float v) { return __builtin_bit_cast(f16x2, v); }
__device__ __forceinline__ f16x2 bcu(unsigned int v) { return __builtin_bit_cast(f16x2, v); }
__device__ __forceinline__ unsigned int packh(float a, float b) {
    return (unsigned int)f2h(a) | ((unsigned int)f2h(b) << 16);
}

// ---------------- stage 1: xg = x @ Wx + bias, f16 (verified R6-R11) -------
__global__ __launch_bounds__(256) void xg_gemm(
    const float* __restrict__ x, const float* __restrict__ Wx,
    const float* __restrict__ bias, unsigned short* __restrict__ xg)
{
    __shared__ float xs[32][65];
    __shared__ float wsl[64][256];

    const int tid = threadIdx.x;
    const long r0 = (long)blockIdx.x * 32;
    const int  c0 = blockIdx.y * 256;

    {
        const float4* src = (const float4*)(x + r0 * Dd);
        float4 v0 = src[tid], v1 = src[tid + 256];
        int e = tid * 4;
        xs[e >> 6][e & 63] = v0.x; xs[e >> 6][(e & 63) + 1] = v0.y;
        xs[e >> 6][(e & 63) + 2] = v0.z; xs[e >> 6][(e & 63) + 3] = v0.w;
        e += 1024;
        xs[e >> 6][e & 63] = v1.x; xs[e >> 6][(e & 63) + 1] = v1.y;
        xs[e >> 6][(e & 63) + 2] = v1.z; xs[e >> 6][(e & 63) + 3] = v1.w;
    }
    for (int i = tid; i < 64 * 64; i += 256) {
        int d = i >> 6, cq = i & 63;
        *(float4*)&wsl[d][cq * 4] = *(const float4*)(Wx + (long)d * G4 + c0 + cq * 4);
    }
    __syncthreads();

    const int r = tid & 31, cg = tid >> 5;
    float acc[32];
    #pragma unroll
    for (int c = 0; c < 32; ++c) acc[c] = bias[c0 + cg * 32 + c];
    for (int k = 0; k < 64; ++k) {
        float xv = xs[r][k];
        #pragma unroll
        for (int c = 0; c < 32; ++c) acc[c] += xv * wsl[k][cg * 32 + c];
    }
    unsigned int ow[16];
    #pragma unroll
    for (int c2 = 0; c2 < 16; ++c2)
        ow[c2] = packh(acc[2 * c2], acc[2 * c2 + 1]);
    uint4* dst = (uint4*)(xg + (r0 + r) * G4 + c0 + cg * 32);
    dst[0] = make_uint4(ow[0], ow[1], ow[2], ow[3]);
    dst[1] = make_uint4(ow[4], ow[5], ow[6], ow[7]);
    dst[2] = make_uint4(ow[8], ow[9], ow[10], ow[11]);
    dst[3] = make_uint4(ow[12], ow[13], ow[14], ow[15]);
}

// ---------------- stage 2: recurrence -------------------------------------
// pair i covers k = 2i,2i+1; cols A,B,C,D = gates i,f,g,o of unit tid.

#define WLOADV4(i) \
  const f16x2 wA_##i = f16x2{(_Float16)Wh[(2*(i))*G4 + colA], (_Float16)Wh[(2*(i)+1)*G4 + colA]}; \
  const f16x2 wB_##i = f16x2{(_Float16)Wh[(2*(i))*G4 + colB], (_Float16)Wh[(2*(i)+1)*G4 + colB]}; \
  const f16x2 wC_##i = f16x2{(_Float16)Wh[(2*(i))*G4 + colC], (_Float16)Wh[(2*(i)+1)*G4 + colC]}; \
  const f16x2 wD_##i = f16x2{(_Float16)Wh[(2*(i))*G4 + colD], (_Float16)Wh[(2*(i)+1)*G4 + colD]};

#define AW1(dst, cix, i) { \
    f16x2 t_ = f16x2{(_Float16)Wh[(2*(i))*G4 + (cix)], (_Float16)Wh[(2*(i)+1)*G4 + (cix)]}; \
    asm volatile("v_accvgpr_write_b32 %0, %1" : "=a"(dst) : "v"(__builtin_bit_cast(float, t_))); }

#define WLOADA4(i) \
  float awA_##i, awB_##i, awC_##i, awD_##i; \
  AW1(awA_##i, colA, i) AW1(awB_##i, colB, i) \
  AW1(awC_##i, colC, i) AW1(awD_##i, colD, i)

#define REPV32(M) \
  M(0) M(1) M(2) M(3) M(4) M(5) M(6) M(7) \
  M(8) M(9) M(10) M(11) M(12) M(13) M(14) M(15) \
  M(16) M(17) M(18) M(19) M(20) M(21) M(22) M(23) \
  M(24) M(25) M(26) M(27) M(28) M(29) M(30) M(31)

#define REPA64(M) \
  M(32) M(33) M(34) M(35) M(36) M(37) M(38) M(39) \
  M(40) M(41) M(42) M(43) M(44) M(45) M(46) M(47) \
  M(48) M(49) M(50) M(51) M(52) M(53) M(54) M(55) \
  M(56) M(57) M(58) M(59) M(60) M(61) M(62) M(63) \
  M(64) M(65) M(66) M(67) M(68) M(69) M(70) M(71) \
  M(72) M(73) M(74) M(75) M(76) M(77) M(78) M(79) \
  M(80) M(81) M(82) M(83) M(84) M(85) M(86) M(87) \
  M(88) M(89) M(90) M(91) M(92) M(93) M(94) M(95)

#define DOTPV(i, hh) { f16x2 h_ = (hh); \
    aA = dot2(h_, wA_##i, aA); aB = dot2(h_, wB_##i, aB); \
    aC = dot2(h_, wC_##i, aC); aD = dot2(h_, wD_##i, aD); }

// V group with rotating h slot: dots on slot, then slot <- group n's h
#define GV(s, n, i0,i1,i2,i3) { \
    DOTPV(i0, bcf(s.x)) DOTPV(i1, bcf(s.y)) \
    DOTPV(i2, bcf(s.z)) DOTPV(i3, bcf(s.w)) \
    s = hvf4[n]; }

// AGPR read (volatile pins program-order placement)
#define ARD(dst, src) \
    asm volatile("v_accvgpr_read_b32 %0, %1" : "=v"(dst) : "a"(src));

// read group (i0..i3)'s 16 AGPR weights into bank bk temps
#define AREADG(bk, i0,i1,i2,i3) \
    ARD(qA##bk##_0, awA_##i0) ARD(qB##bk##_0, awB_##i0) ARD(qC##bk##_0, awC_##i0) ARD(qD##bk##_0, awD_##i0) \
    ARD(qA##bk##_1, awA_##i1) ARD(qB##bk##_1, awB_##i1) ARD(qC##bk##_1, awC_##i1) ARD(qD##bk##_1, awD_##i1) \
    ARD(qA##bk##_2, awA_##i2) ARD(qB##bk##_2, awB_##i2) ARD(qC##bk##_2, awC_##i2) ARD(qD##bk##_2, awD_##i2) \
    ARD(qA##bk##_3, awA_##i3) ARD(qB##bk##_3, awB_##i3) ARD(qC##bk##_3, awC_##i3) ARD(qD##bk##_3, awD_##i3)

// dot bank bk temps against h slot hs (pair j <-> component j)
#define ADOTSG(bk, hs) { \
    f16x2 h0 = bcf(hs.x), h1 = bcf(hs.y), h2 = bcf(hs.z), h3 = bcf(hs.w); \
    aA = dot2(h0, bcf(qA##bk##_0), aA); aB = dot2(h0, bcf(qB##bk##_0), aB); \
    aC = dot2(h0, bcf(qC##bk##_0), aC); aD = dot2(h0, bcf(qD##bk##_0), aD); \
    aA = dot2(h1, bcf(qA##bk##_1), aA); aB = dot2(h1, bcf(qB##bk##_1), aB); \
    aC = dot2(h1, bcf(qC##bk##_1), aC); aD = dot2(h1, bcf(qD##bk##_1), aD); \
    aA = dot2(h2, bcf(qA##bk##_2), aA); aB = dot2(h2, bcf(qB##bk##_2), aB); \
    aC = dot2(h2, bcf(qC##bk##_2), aC); aD = dot2(h2, bcf(qD##bk##_2), aD); \
    aA = dot2(h3, bcf(qA##bk##_3), aA); aB = dot2(h3, bcf(qB##bk##_3), aB); \
    aC = dot2(h3, bcf(qC##bk##_3), aC); aD = dot2(h3, bcf(qD##bk##_3), aD); }

// tail-weight double-buffer load (slot token s = 0/1)
#define TWL(s, jq) { twA##s = wl4[jq][colA]; twB##s = wl4[jq][colB]; \
                     twC##s = wl4[jq][colC]; twD##s = wl4[jq][colD]; }

// tail group: 16 dots from uint4 weight slot s against h slot hs
#define GT(hs, s) { \
    f16x2 h0 = bcf(hs.x), h1 = bcf(hs.y), h2 = bcf(hs.z), h3 = bcf(hs.w); \
    aA = dot2(h0, bcu(twA##s.x), aA); aA = dot2(h1, bcu(twA##s.y), aA); \
    aA = dot2(h2, bcu(twA##s.z), aA); aA = dot2(h3, bcu(twA##s.w), aA); \
    aB = dot2(h0, bcu(twB##s.x), aB); aB = dot2(h1, bcu(twB##s.y), aB); \
    aB = dot2(h2, bcu(twB##s.z), aB); aB = dot2(h3, bcu(twB##s.w), aB); \
    aC = dot2(h0, bcu(twC##s.x), aC); aC = dot2(h1, bcu(twC##s.y), aC); \
    aC = dot2(h2, bcu(twC##s.z), aC); aC = dot2(h3, bcu(twC##s.w), aC); \
    aD = dot2(h0, bcu(twD##s.x), aD); aD = dot2(h1, bcu(twD##s.y), aD); \
    aD = dot2(h2, bcu(twD##s.z), aD); aD = dot2(h3, bcu(twD##s.w), aD); }

__global__ __launch_bounds__(256, 1) void lstm_xg(
    const unsigned short* __restrict__ xg,  // [B,T,1024] f16, bias folded
    const float* __restrict__ Wh,           // [H,4H]
    const float* __restrict__ Wout,         // [H,C]
    const float* __restrict__ bout,         // [C]
    float* __restrict__ out)                // [B,T,C]
{
    __shared__ alignas(16) unsigned short h_buf[2][Hh];  // double-buffered h
    __shared__ uint4 wl4[8][G4];       // tail pairs 96..127, 128 KB
    __shared__ float wout_t[Cc][Hh];
    __shared__ float bout_l[8];

    const int tid  = threadIdx.x;
    const int b    = blockIdx.x;
    const int colA = tid;          // gate i of unit tid
    const int colB = tid + 256;    // f
    const int colC = tid + 512;    // g
    const int colD = tid + 768;    // o

    // ---- prologue: 128 V-regs + 256 AGPRs + packed LDS tail ----
    REPV32(WLOADV4)
    REPA64(WLOADA4)

    #pragma unroll
    for (int jq = 0; jq < 8; ++jq) {   // tail: k rows 192+8jq .. 192+8jq+7
        const int kb = 192 + 8 * jq;
        wl4[jq][colA] = make_uint4(
            packh(Wh[(kb+0)*G4 + colA], Wh[(kb+1)*G4 + colA]),
            packh(Wh[(kb+2)*G4 + colA], Wh[(kb+3)*G4 + colA]),
            packh(Wh[(kb+4)*G4 + colA], Wh[(kb+5)*G4 + colA]),
            packh(Wh[(kb+6)*G4 + colA], Wh[(kb+7)*G4 + colA]));
        wl4[jq][colB] = make_uint4(
            packh(Wh[(kb+0)*G4 + colB], Wh[(kb+1)*G4 + colB]),
            packh(Wh[(kb+2)*G4 + colB], Wh[(kb+3)*G4 + colB]),
            packh(Wh[(kb+4)*G4 + colB], Wh[(kb+5)*G4 + colB]),
            packh(Wh[(kb+6)*G4 + colB], Wh[(kb+7)*G4 + colB]));
        wl4[jq][colC] = make_uint4(
            packh(Wh[(kb+0)*G4 + colC], Wh[(kb+1)*G4 + colC]),
            packh(Wh[(kb+2)*G4 + colC], Wh[(kb+3)*G4 + colC]),
            packh(Wh[(kb+4)*G4 + colC], Wh[(kb+5)*G4 + colC]),
            packh(Wh[(kb+6)*G4 + colC], Wh[(kb+7)*G4 + colC]));
        wl4[jq][colD] = make_uint4(
            packh(Wh[(kb+0)*G4 + colD], Wh[(kb+1)*G4 + colD]),
            packh(Wh[(kb+2)*G4 + colD], Wh[(kb+3)*G4 + colD]),
            packh(Wh[(kb+4)*G4 + colD], Wh[(kb+5)*G4 + colD]),
            packh(Wh[(kb+6)*G4 + colD], Wh[(kb+7)*G4 + colD]));
    }
    h_buf[0][tid] = 0;
    for (int i = tid; i < Cc * Hh; i += 256) wout_t[i % Cc][i / Cc] = Wout[i];
    if (tid < Cc) bout_l[tid] = bout[tid];

    const unsigned short* xgB = xg + (long)b * Tt * G4;
    unsigned short xgA = xgB[colA], xgBv = xgB[colB];
    unsigned short xgC = xgB[colC], xgD = xgB[colD];
    float c_state = 0.0f;
    int par = 0;
    __syncthreads();

    // ---- time loop (one barrier/step; fully pipelined operand flow) ----
    for (int t = 0; t < Tt; ++t) {
        unsigned short nA = 0, nB = 0, nC = 0, nD = 0;
        if (t + 1 < Tt) {
            const unsigned short* xn = xgB + (long)(t + 1) * G4;
            nA = xn[colA]; nB = xn[colB]; nC = xn[colC]; nD = xn[colD];
        }

        const float4* hvf4 = (const float4*)h_buf[par];  // h(t-1), broadcast
        float aA = 0.f, aB = 0.f, aC = 0.f, aD = 0.f;

        // AGPR-read banks (2 x 16 temps) and tail-weight banks
        float qA0_0, qB0_0, qC0_0, qD0_0, qA0_1, qB0_1, qC0_1, qD0_1;
        float qA0_2, qB0_2, qC0_2, qD0_2, qA0_3, qB0_3, qC0_3, qD0_3;
        float qA1_0, qB1_0, qC1_0, qD1_0, qA1_1, qB1_1, qC1_1, qD1_1;
        float qA1_2, qB1_2, qC1_2, qD1_2, qA1_3, qB1_3, qC1_3, qD1_3;
        uint4 twA0, twB0, twC0, twD0, twA1, twB1, twC1, twD1;

        // 4 rotating h slots, primed 4 groups deep
        float4 hs0 = hvf4[0], hs1 = hvf4[1], hs2 = hvf4[2], hs3 = hvf4[3];

        // V groups: pairs 0..31 (h groups 0..7), h loads 4..11 run ahead
        GV(hs0, 4,   0, 1, 2, 3)   GV(hs1, 5,   4, 5, 6, 7)
        GV(hs2, 6,   8, 9,10,11)   GV(hs3, 7,  12,13,14,15)
        GV(hs0, 8,  16,17,18,19)   GV(hs1, 9,  20,21,22,23)
        GV(hs2, 10, 24,25,26,27)   GV(hs3, 11, 28,29,30,31)

        // A bank pipeline: reads for group k+1 precede dots of group k
        AREADG(0, 32,33,34,35)
        AREADG(1, 36,37,38,39)  ADOTSG(0, hs0)  hs0 = hvf4[12];
        AREADG(0, 40,41,42,43)  ADOTSG(1, hs1)  hs1 = hvf4[13];
        AREADG(1, 44,45,46,47)  ADOTSG(0, hs2)  hs2 = hvf4[14];
        AREADG(0, 48,49,50,51)  ADOTSG(1, hs3)  hs3 = hvf4[15];
        AREADG(1, 52,53,54,55)  ADOTSG(0, hs0)  hs0 = hvf4[16];
        AREADG(0, 56,57,58,59)  ADOTSG(1, hs1)  hs1 = hvf4[17];
        AREADG(1, 60,61,62,63)  ADOTSG(0, hs2)  hs2 = hvf4[18];
        AREADG(0, 64,65,66,67)  ADOTSG(1, hs3)  hs3 = hvf4[19];
        AREADG(1, 68,69,70,71)  ADOTSG(0, hs0)  hs0 = hvf4[20];
        AREADG(0, 72,73,74,75)  ADOTSG(1, hs1)  hs1 = hvf4[21];
        AREADG(1, 76,77,78,79)  ADOTSG(0, hs2)  hs2 = hvf4[22];
        AREADG(0, 80,81,82,83)  ADOTSG(1, hs3)  hs3 = hvf4[23];
        AREADG(1, 84,85,86,87)  ADOTSG(0, hs0)  hs0 = hvf4[24];
        TWL(0, 0)
        AREADG(0, 88,89,90,91)  ADOTSG(1, hs1)  hs1 = hvf4[25];
        TWL(1, 1)
        AREADG(1, 92,93,94,95)  ADOTSG(0, hs2)  hs2 = hvf4[26];
                                ADOTSG(1, hs3)  hs3 = hvf4[27];

        // tail: pairs 96..127 (h groups 24..31), weights double-buffered
        GT(hs0, 0)  TWL(0, 2)  hs0 = hvf4[28];
        GT(hs1, 1)  TWL(1, 3)  hs1 = hvf4[29];
        GT(hs2, 0)  TWL(0, 4)  hs2 = hvf4[30];
        GT(hs3, 1)  TWL(1, 5)  hs3 = hvf4[31];
        GT(hs0, 0)  TWL(0, 6)
        GT(hs1, 1)  TWL(1, 7)
        GT(hs2, 0)
        GT(hs3, 1)

        float ig = sigm(h2f(xgA) + aA);
        float fg = sigm(h2f(xgBv) + aB);
        float gg = tanh_fast(h2f(xgC) + aC);
        float og = sigm(h2f(xgD) + aD);
        c_state = fg * c_state + ig * gg;
        float hval = og * tanh_fast(c_state);

        h_buf[par ^ 1][tid] = f2h(hval);
        __syncthreads();   // h(t) visible; h(t-1) reads all complete

        // fused output projection: wave w -> class w; waves 0,1 also 4,5
        const unsigned short* hn = h_buf[par ^ 1];
        const int w = tid >> 6, l = tid & 63;
        {
            float p = 0.0f;
            #pragma unroll
            for (int j = 0; j < 4; ++j)
                p += h2f(hn[l + 64 * j]) * wout_t[w][l + 64 * j];
            #pragma unroll
            for (int off = 32; off > 0; off >>= 1) p += __shfl_down(p, off);
            if (l == 0) out[((long)b * Tt + t) * Cc + w] = p + bout_l[w];
        }
        if (w < 2) {
            const int c2 = 4 + w;
            float p = 0.0f;
            #pragma unroll
            for (int j = 0; j < 4; ++j)
                p += h2f(hn[l + 64 * j]) * wout_t[c2][l + 64 * j];
            #pragma unroll
            for (int off = 32; off > 0; off >>= 1) p += __shfl_down(p, off);
            if (l == 0) out[((long)b * Tt + t) * Cc + c2] = p + bout_l[c2];
        }

        xgA = nA; xgBv = nB; xgC = nC; xgD = nD;
        par ^= 1;
    }
}

// ---------------- fallback: R2 single-block kernel (no ws needed) ----------
__global__ __launch_bounds__(1024) void lstm_fused(
    const float* __restrict__ x, const float* __restrict__ Wx,
    const float* __restrict__ Wh, const float* __restrict__ bias,
    const float* __restrict__ Wout, const float* __restrict__ bout,
    float* __restrict__ out)
{
    __shared__ float h_lds[Hh];
    __shared__ float gates_lds[G4];
    __shared__ float x_lds[2][Dd];
    __shared__ float wout_t[Cc][Hh];
    __shared__ float bout_l[Cc];
    const int tid = threadIdx.x;
    const int b   = blockIdx.x;
    float wx[Dd];
    #pragma unroll
    for (int d = 0; d < Dd; ++d) wx[d] = Wx[d * G4 + tid];
    const float bj = bias[tid];
    if (tid < Hh) h_lds[tid] = 0.0f;
    for (int i = tid; i < Cc * Hh; i += 1024) wout_t[i % Cc][i / Cc] = Wout[i];
    if (tid < Cc) bout_l[tid] = bout[tid];
    const float* xB = x + (long)b * Tt * Dd;
    if (tid < Dd) x_lds[0][tid] = xB[tid];
    float c_state = 0.0f;
    __syncthreads();
    const float* WhB = Wh + tid;
    for (int t = 0; t < Tt; ++t) {
        float gg = bj;
        const float* xr = x_lds[t & 1];
        #pragma unroll
        for (int d = 0; d < Dd; ++d) gg += xr[d] * wx[d];
        #pragma unroll 8
        for (int k = 0; k < Hh; ++k) gg += h_lds[k] * WhB[k * G4];
        float a;
        if (tid < 2 * Hh)      a = 1.0f / (1.0f + expf(-gg));
        else if (tid < 3 * Hh) a = tanhf(gg);
        else                   a = 1.0f / (1.0f + expf(-gg));
        gates_lds[tid] = a;
        __syncthreads();
        if (tid < Hh) {
            float iv = gates_lds[tid], fv = gates_lds[tid + Hh];
            float gv = gates_lds[tid + 2 * Hh], ov = gates_lds[tid + 3 * Hh];
            c_state = fv * c_state + iv * gv;
            h_lds[tid] = ov * tanhf(c_state);
        } else if (tid >= 384 && tid < 448) {
            int tn = t + 1;
            if (tn < Tt) x_lds[tn & 1][tid - 384] = xB[(long)tn * Dd + (tid - 384)];
        }
        __syncthreads();
        const int w = tid >> 6, l = tid & 63;
        if (w < Cc) {
            float p = 0.0f;
            #pragma unroll
            for (int qq = 0; qq < 4; ++qq) p += h_lds[l + 64 * qq] * wout_t[w][l + 64 * qq];
            #pragma unroll
            for (int off = 32; off > 0; off >>= 1) p += __shfl_down(p, off);
            if (l == 0) out[((long)b * Tt + t) * Cc + w] = p + bout_l[w];
        }
    }
}

extern "C" void kernel_launch(void* const* d_in, const int* in_sizes, int n_in,
                              void* d_out, int out_size, void* d_ws, size_t ws_size,
                              hipStream_t stream) {
    const float* x    = (const float*)d_in[0];
    const float* Wx   = (const float*)d_in[1];
    const float* Wh   = (const float*)d_in[2];
    const float* bvec = (const float*)d_in[3];
    const float* Wout = (const float*)d_in[4];
    const float* bout = (const float*)d_in[5];
    float* outp = (float*)d_out;

    if (ws_size >= XG_BYTES) {
        unsigned short* xgws = (unsigned short*)d_ws;
        xg_gemm<<<dim3(BT / 32, 4), dim3(256), 0, stream>>>(x, Wx, bvec, xgws);
        lstm_xg<<<dim3(128), dim3(256), 0, stream>>>(xgws, Wh, Wout, bout, outp);
    } else {
        lstm_fused<<<dim3(128), dim3(1024), 0, stream>>>(x, Wx, Wh, bvec, Wout, bout, outp);
    }
}

// Round 15
// 3308.993 us; speedup vs baseline: 15.3261x; 1.0008x over previous
//
#include <hip/hip_runtime.h>
#include <math.h>

// LSTM B=128,T=1024,D=64,H=256,C=6 — R14: R10 base + explicit SW pipeline.
//
// ISA fact (R13): v_dot2_f32_f16 cannot source AGPRs; only MFMA reads AGPRs
// directly. So weights in AGPR must round-trip via v_accvgpr_read (R10 path).
// R10 = 3.3us/step @ 0.77us issue -> ~2.5us latency exposure. R14 hides it:
//  * 4 rotating h-slot float4 regs: every LDS h read issued ~4 groups (~160cy)
//    ahead of use (LDS latency ~120cy)
//  * AGPR-read double-buffer: group k+1's 16 v_accvgpr_read issued before
//    group k's dots (volatile asm pins placement)
//  * tail-weight uint4 double-buffer (2-group lead)
// Register audit: 128 wV + 16 hs + 32 qbank + 32 tw + ~30 work ~= 240 < 256.
// Numerics identical to R8-R10 (f16 weights/h/xg, fp32 accum): absmax 3.9e-3.

#define Tt 1024
#define Dd 64
#define Hh 256
#define G4 1024
#define Cc 6
#define BT (128 * 1024)
#define XG_BYTES ((size_t)BT * G4 * 2)   // 256 MB f16

typedef _Float16 f16x2 __attribute__((ext_vector_type(2)));

__device__ __forceinline__ float dot2(f16x2 a, f16x2 b, float c) {
#if __has_builtin(__builtin_amdgcn_fdot2)
    return __builtin_amdgcn_fdot2(a, b, c, false);
#else
    return c + (float)a.x * (float)b.x + (float)a.y * (float)b.y;
#endif
}
__device__ __forceinline__ float sigm(float p) { return 1.0f / (1.0f + __expf(-p)); }
__device__ __forceinline__ float tanh_fast(float p) {
    return 1.0f - 2.0f / (__expf(2.0f * p) + 1.0f);
}
__device__ __forceinline__ unsigned short f2h(float v) {
    _Float16 h = (_Float16)v;
    return __builtin_bit_cast(unsigned short, h);
}
__device__ __forceinline__ float h2f(unsigned short u) {
    return (float)__builtin_bit_cast(_Float16, u);
}
__device__ __forceinline__ f16x2 bcf(float v) { return __builtin_bit_cast(f16x2, v); }
__device__ __forceinline__ f16x2 bcu(unsigned int v) { return __builtin_bit_cast(f16x2, v); }
__device__ __forceinline__ unsigned int packh(float a, float b) {
    return (unsigned int)f2h(a) | ((unsigned int)f2h(b) << 16);
}

// ---------------- stage 1: xg = x @ Wx + bias, f16 (verified R6-R11) -------
__global__ __launch_bounds__(256) void xg_gemm(
    const float* __restrict__ x, const float* __restrict__ Wx,
    const float* __restrict__ bias, unsigned short* __restrict__ xg)
{
    __shared__ float xs[32][65];
    __shared__ float wsl[64][256];

    const int tid = threadIdx.x;
    const long r0 = (long)blockIdx.x * 32;
    const int  c0 = blockIdx.y * 256;

    {
        const float4* src = (const float4*)(x + r0 * Dd);
        float4 v0 = src[tid], v1 = src[tid + 256];
        int e = tid * 4;
        xs[e >> 6][e & 63] = v0.x; xs[e >> 6][(e & 63) + 1] = v0.y;
        xs[e >> 6][(e & 63) + 2] = v0.z; xs[e >> 6][(e & 63) + 3] = v0.w;
        e += 1024;
        xs[e >> 6][e & 63] = v1.x; xs[e >> 6][(e & 63) + 1] = v1.y;
        xs[e >> 6][(e & 63) + 2] = v1.z; xs[e >> 6][(e & 63) + 3] = v1.w;
    }
    for (int i = tid; i < 64 * 64; i += 256) {
        int d = i >> 6, cq = i & 63;
        *(float4*)&wsl[d][cq * 4] = *(const float4*)(Wx + (long)d * G4 + c0 + cq * 4);
    }
    __syncthreads();

    const int r = tid & 31, cg = tid >> 5;
    float acc[32];
    #pragma unroll
    for (int c = 0; c < 32; ++c) acc[c] = bias[c0 + cg * 32 + c];
    for (int k = 0; k < 64; ++k) {
        float xv = xs[r][k];
        #pragma unroll
        for (int c = 0; c < 32; ++c) acc[c] += xv * wsl[k][cg * 32 + c];
    }
    unsigned int ow[16];
    #pragma unroll
    for (int c2 = 0; c2 < 16; ++c2)
        ow[c2] = packh(acc[2 * c2], acc[2 * c2 + 1]);
    uint4* dst = (uint4*)(xg + (r0 + r) * G4 + c0 + cg * 32);
    dst[0] = make_uint4(ow[0], ow[1], ow[2], ow[3]);
    dst[1] = make_uint4(ow[4], ow[5], ow[6], ow[7]);
    dst[2] = make_uint4(ow[8], ow[9], ow[10], ow[11]);
    dst[3] = make_uint4(ow[12], ow[13], ow[14], ow[15]);
}

// ---------------- stage 2: recurrence -------------------------------------
// pair i covers k = 2i,2i+1; cols A,B,C,D = gates i,f,g,o of unit tid.

#define WLOADV4(i) \
  const f16x2 wA_##i = f16x2{(_Float16)Wh[(2*(i))*G4 + colA], (_Float16)Wh[(2*(i)+1)*G4 + colA]}; \
  const f16x2 wB_##i = f16x2{(_Float16)Wh[(2*(i))*G4 + colB], (_Float16)Wh[(2*(i)+1)*G4 + colB]}; \
  const f16x2 wC_##i = f16x2{(_Float16)Wh[(2*(i))*G4 + colC], (_Float16)Wh[(2*(i)+1)*G4 + colC]}; \
  const f16x2 wD_##i = f16x2{(_Float16)Wh[(2*(i))*G4 + colD], (_Float16)Wh[(2*(i)+1)*G4 + colD]};

#define AW1(dst, cix, i) { \
    f16x2 t_ = f16x2{(_Float16)Wh[(2*(i))*G4 + (cix)], (_Float16)Wh[(2*(i)+1)*G4 + (cix)]}; \
    asm volatile("v_accvgpr_write_b32 %0, %1" : "=a"(dst) : "v"(__builtin_bit_cast(float, t_))); }

#define WLOADA4(i) \
  float awA_##i, awB_##i, awC_##i, awD_##i; \
  AW1(awA_##i, colA, i) AW1(awB_##i, colB, i) \
  AW1(awC_##i, colC, i) AW1(awD_##i, colD, i)

#define REPV32(M) \
  M(0) M(1) M(2) M(3) M(4) M(5) M(6) M(7) \
  M(8) M(9) M(10) M(11) M(12) M(13) M(14) M(15) \
  M(16) M(17) M(18) M(19) M(20) M(21) M(22) M(23) \
  M(24) M(25) M(26) M(27) M(28) M(29) M(30) M(31)

#define REPA64(M) \
  M(32) M(33) M(34) M(35) M(36) M(37) M(38) M(39) \
  M(40) M(41) M(42) M(43) M(44) M(45) M(46) M(47) \
  M(48) M(49) M(50) M(51) M(52) M(53) M(54) M(55) \
  M(56) M(57) M(58) M(59) M(60) M(61) M(62) M(63) \
  M(64) M(65) M(66) M(67) M(68) M(69) M(70) M(71) \
  M(72) M(73) M(74) M(75) M(76) M(77) M(78) M(79) \
  M(80) M(81) M(82) M(83) M(84) M(85) M(86) M(87) \
  M(88) M(89) M(90) M(91) M(92) M(93) M(94) M(95)

#define DOTPV(i, hh) { f16x2 h_ = (hh); \
    aA = dot2(h_, wA_##i, aA); aB = dot2(h_, wB_##i, aB); \
    aC = dot2(h_, wC_##i, aC); aD = dot2(h_, wD_##i, aD); }

// V group with rotating h slot: dots on slot, then slot <- group n's h
#define GV(s, n, i0,i1,i2,i3) { \
    DOTPV(i0, bcf(s.x)) DOTPV(i1, bcf(s.y)) \
    DOTPV(i2, bcf(s.z)) DOTPV(i3, bcf(s.w)) \
    s = hvf4[n]; }

// AGPR read (volatile pins program-order placement)
#define ARD(dst, src) \
    asm volatile("v_accvgpr_read_b32 %0, %1" : "=v"(dst) : "a"(src));

// read group (i0..i3)'s 16 AGPR weights into bank bk temps
#define AREADG(bk, i0,i1,i2,i3) \
    ARD(qA##bk##_0, awA_##i0) ARD(qB##bk##_0, awB_##i0) ARD(qC##bk##_0, awC_##i0) ARD(qD##bk##_0, awD_##i0) \
    ARD(qA##bk##_1, awA_##i1) ARD(qB##bk##_1, awB_##i1) ARD(qC##bk##_1, awC_##i1) ARD(qD##bk##_1, awD_##i1) \
    ARD(qA##bk##_2, awA_##i2) ARD(qB##bk##_2, awB_##i2) ARD(qC##bk##_2, awC_##i2) ARD(qD##bk##_2, awD_##i2) \
    ARD(qA##bk##_3, awA_##i3) ARD(qB##bk##_3, awB_##i3) ARD(qC##bk##_3, awC_##i3) ARD(qD##bk##_3, awD_##i3)

// dot bank bk temps against h slot hs (pair j <-> component j)
#define ADOTSG(bk, hs) { \
    f16x2 h0 = bcf(hs.x), h1 = bcf(hs.y), h2 = bcf(hs.z), h3 = bcf(hs.w); \
    aA = dot2(h0, bcf(qA##bk##_0), aA); aB = dot2(h0, bcf(qB##bk##_0), aB); \
    aC = dot2(h0, bcf(qC##bk##_0), aC); aD = dot2(h0, bcf(qD##bk##_0), aD); \
    aA = dot2(h1, bcf(qA##bk##_1), aA); aB = dot2(h1, bcf(qB##bk##_1), aB); \
    aC = dot2(h1, bcf(qC##bk##_1), aC); aD = dot2(h1, bcf(qD##bk##_1), aD); \
    aA = dot2(h2, bcf(qA##bk##_2), aA); aB = dot2(h2, bcf(qB##bk##_2), aB); \
    aC = dot2(h2, bcf(qC##bk##_2), aC); aD = dot2(h2, bcf(qD##bk##_2), aD); \
    aA = dot2(h3, bcf(qA##bk##_3), aA); aB = dot2(h3, bcf(qB##bk##_3), aB); \
    aC = dot2(h3, bcf(qC##bk##_3), aC); aD = dot2(h3, bcf(qD##bk##_3), aD); }

// tail-weight double-buffer load (slot token s = 0/1)
#define TWL(s, jq) { twA##s = wl4[jq][colA]; twB##s = wl4[jq][colB]; \
                     twC##s = wl4[jq][colC]; twD##s = wl4[jq][colD]; }

// tail group: 16 dots from uint4 weight slot s against h slot hs
#define GT(hs, s) { \
    f16x2 h0 = bcf(hs.x), h1 = bcf(hs.y), h2 = bcf(hs.z), h3 = bcf(hs.w); \
    aA = dot2(h0, bcu(twA##s.x), aA); aA = dot2(h1, bcu(twA##s.y), aA); \
    aA = dot2(h2, bcu(twA##s.z), aA); aA = dot2(h3, bcu(twA##s.w), aA); \
    aB = dot2(h0, bcu(twB##s.x), aB); aB = dot2(h1, bcu(twB##s.y), aB); \
    aB = dot2(h2, bcu(twB##s.z), aB); aB = dot2(h3, bcu(twB##s.w), aB); \
    aC = dot2(h0, bcu(twC##s.x), aC); aC = dot2(h1, bcu(twC##s.y), aC); \
    aC = dot2(h2, bcu(twC##s.z), aC); aC = dot2(h3, bcu(twC##s.w), aC); \
    aD = dot2(h0, bcu(twD##s.x), aD); aD = dot2(h1, bcu(twD##s.y), aD); \
    aD = dot2(h2, bcu(twD##s.z), aD); aD = dot2(h3, bcu(twD##s.w), aD); }

__global__ __launch_bounds__(256, 1) void lstm_xg(
    const unsigned short* __restrict__ xg,  // [B,T,1024] f16, bias folded
    const float* __restrict__ Wh,           // [H,4H]
    const float* __restrict__ Wout,         // [H,C]
    const float* __restrict__ bout,         // [C]
    float* __restrict__ out)                // [B,T,C]
{
    __shared__ alignas(16) unsigned short h_buf[2][Hh];  // double-buffered h
    __shared__ uint4 wl4[8][G4];       // tail pairs 96..127, 128 KB
    __shared__ float wout_t[Cc][Hh];
    __shared__ float bout_l[8];

    const int tid  = threadIdx.x;
    const int b    = blockIdx.x;
    const int colA = tid;          // gate i of unit tid
    const int colB = tid + 256;    // f
    const int colC = tid + 512;    // g
    const int colD = tid + 768;    // o

    // ---- prologue: 128 V-regs + 256 AGPRs + packed LDS tail ----
    REPV32(WLOADV4)
    REPA64(WLOADA4)

    #pragma unroll
    for (int jq = 0; jq < 8; ++jq) {   // tail: k rows 192+8jq .. 192+8jq+7
        const int kb = 192 + 8 * jq;
        wl4[jq][colA] = make_uint4(
            packh(Wh[(kb+0)*G4 + colA], Wh[(kb+1)*G4 + colA]),
            packh(Wh[(kb+2)*G4 + colA], Wh[(kb+3)*G4 + colA]),
            packh(Wh[(kb+4)*G4 + colA], Wh[(kb+5)*G4 + colA]),
            packh(Wh[(kb+6)*G4 + colA], Wh[(kb+7)*G4 + colA]));
        wl4[jq][colB] = make_uint4(
            packh(Wh[(kb+0)*G4 + colB], Wh[(kb+1)*G4 + colB]),
            packh(Wh[(kb+2)*G4 + colB], Wh[(kb+3)*G4 + colB]),
            packh(Wh[(kb+4)*G4 + colB], Wh[(kb+5)*G4 + colB]),
            packh(Wh[(kb+6)*G4 + colB], Wh[(kb+7)*G4 + colB]));
        wl4[jq][colC] = make_uint4(
            packh(Wh[(kb+0)*G4 + colC], Wh[(kb+1)*G4 + colC]),
            packh(Wh[(kb+2)*G4 + colC], Wh[(kb+3)*G4 + colC]),
            packh(Wh[(kb+4)*G4 + colC], Wh[(kb+5)*G4 + colC]),
            packh(Wh[(kb+6)*G4 + colC], Wh[(kb+7)*G4 + colC]));
        wl4[jq][colD] = make_uint4(
            packh(Wh[(kb+0)*G4 + colD], Wh[(kb+1)*G4 + colD]),
            packh(Wh[(kb+2)*G4 + colD], Wh[(kb+3)*G4 + colD]),
            packh(Wh[(kb+4)*G4 + colD], Wh[(kb+5)*G4 + colD]),
            packh(Wh[(kb+6)*G4 + colD], Wh[(kb+7)*G4 + colD]));
    }
    h_buf[0][tid] = 0;
    for (int i = tid; i < Cc * Hh; i += 256) wout_t[i % Cc][i / Cc] = Wout[i];
    if (tid < Cc) bout_l[tid] = bout[tid];

    const unsigned short* xgB = xg + (long)b * Tt * G4;
    unsigned short xgA = xgB[colA], xgBv = xgB[colB];
    unsigned short xgC = xgB[colC], xgD = xgB[colD];
    float c_state = 0.0f;
    int par = 0;
    __syncthreads();

    // ---- time loop (one barrier/step; fully pipelined operand flow) ----
    for (int t = 0; t < Tt; ++t) {
        unsigned short nA = 0, nB = 0, nC = 0, nD = 0;
        if (t + 1 < Tt) {
            const unsigned short* xn = xgB + (long)(t + 1) * G4;
            nA = xn[colA]; nB = xn[colB]; nC = xn[colC]; nD = xn[colD];
        }

        const float4* hvf4 = (const float4*)h_buf[par];  // h(t-1), broadcast
        float aA = 0.f, aB = 0.f, aC = 0.f, aD = 0.f;

        // AGPR-read banks (2 x 16 temps) and tail-weight banks
        float qA0_0, qB0_0, qC0_0, qD0_0, qA0_1, qB0_1, qC0_1, qD0_1;
        float qA0_2, qB0_2, qC0_2, qD0_2, qA0_3, qB0_3, qC0_3, qD0_3;
        float qA1_0, qB1_0, qC1_0, qD1_0, qA1_1, qB1_1, qC1_1, qD1_1;
        float qA1_2, qB1_2, qC1_2, qD1_2, qA1_3, qB1_3, qC1_3, qD1_3;
        uint4 twA0, twB0, twC0, twD0, twA1, twB1, twC1, twD1;

        // 4 rotating h slots, primed 4 groups deep
        float4 hs0 = hvf4[0], hs1 = hvf4[1], hs2 = hvf4[2], hs3 = hvf4[3];

        // V groups: pairs 0..31 (h groups 0..7), h loads 4..11 run ahead
        GV(hs0, 4,   0, 1, 2, 3)   GV(hs1, 5,   4, 5, 6, 7)
        GV(hs2, 6,   8, 9,10,11)   GV(hs3, 7,  12,13,14,15)
        GV(hs0, 8,  16,17,18,19)   GV(hs1, 9,  20,21,22,23)
        GV(hs2, 10, 24,25,26,27)   GV(hs3, 11, 28,29,30,31)

        // A bank pipeline: reads for group k+1 precede dots of group k
        AREADG(0, 32,33,34,35)
        AREADG(1, 36,37,38,39)  ADOTSG(0, hs0)  hs0 = hvf4[12];
        AREADG(0, 40,41,42,43)  ADOTSG(1, hs1)  hs1 = hvf4[13];
        AREADG(1, 44,45,46,47)  ADOTSG(0, hs2)  hs2 = hvf4[14];
        AREADG(0, 48,49,50,51)  ADOTSG(1, hs3)  hs3 = hvf4[15];
        AREADG(1, 52,53,54,55)  ADOTSG(0, hs0)  hs0 = hvf4[16];
        AREADG(0, 56,57,58,59)  ADOTSG(1, hs1)  hs1 = hvf4[17];
        AREADG(1, 60,61,62,63)  ADOTSG(0, hs2)  hs2 = hvf4[18];
        AREADG(0, 64,65,66,67)  ADOTSG(1, hs3)  hs3 = hvf4[19];
        AREADG(1, 68,69,70,71)  ADOTSG(0, hs0)  hs0 = hvf4[20];
        AREADG(0, 72,73,74,75)  ADOTSG(1, hs1)  hs1 = hvf4[21];
        AREADG(1, 76,77,78,79)  ADOTSG(0, hs2)  hs2 = hvf4[22];
        AREADG(0, 80,81,82,83)  ADOTSG(1, hs3)  hs3 = hvf4[23];
        AREADG(1, 84,85,86,87)  ADOTSG(0, hs0)  hs0 = hvf4[24];
        TWL(0, 0)
        AREADG(0, 88,89,90,91)  ADOTSG(1, hs1)  hs1 = hvf4[25];
        TWL(1, 1)
        AREADG(1, 92,93,94,95)  ADOTSG(0, hs2)  hs2 = hvf4[26];
                                ADOTSG(1, hs3)  hs3 = hvf4[27];

        // tail: pairs 96..127 (h groups 24..31), weights double-buffered
        GT(hs0, 0)  TWL(0, 2)  hs0 = hvf4[28];
        GT(hs1, 1)  TWL(1, 3)  hs1 = hvf4[29];
        GT(hs2, 0)  TWL(0, 4)  hs2 = hvf4[30];
        GT(hs3, 1)  TWL(1, 5)  hs3 = hvf4[31];
        GT(hs0, 0)  TWL(0, 6)
        GT(hs1, 1)  TWL(1, 7)
        GT(hs2, 0)
        GT(hs3, 1)

        float ig = sigm(h2f(xgA) + aA);
        float fg = sigm(h2f(xgBv) + aB);
        float gg = tanh_fast(h2f(xgC) + aC);
        float og = sigm(h2f(xgD) + aD);
        c_state = fg * c_state + ig * gg;
        float hval = og * tanh_fast(c_state);

        h_buf[par ^ 1][tid] = f2h(hval);
        __syncthreads();   // h(t) visible; h(t-1) reads all complete

        // fused output projection: wave w -> class w; waves 0,1 also 4,5
        const unsigned short* hn = h_buf[par ^ 1];
        const int w = tid >> 6, l = tid & 63;
        {
            float p = 0.0f;
            #pragma unroll
            for (int j = 0; j < 4; ++j)
                p += h2f(hn[l + 64 * j]) * wout_t[w][l + 64 * j];
            #pragma unroll
            for (int off = 32; off > 0; off >>= 1) p += __shfl_down(p, off);
            if (l == 0) out[((long)b * Tt + t) * Cc + w] = p + bout_l[w];
        }
        if (w < 2) {
            const int c2 = 4 + w;
            float p = 0.0f;
            #pragma unroll
            for (int j = 0; j < 4; ++j)
                p += h2f(hn[l + 64 * j]) * wout_t[c2][l + 64 * j];
            #pragma unroll
            for (int off = 32; off > 0; off >>= 1) p += __shfl_down(p, off);
            if (l == 0) out[((long)b * Tt + t) * Cc + c2] = p + bout_l[c2];
        }

        xgA = nA; xgBv = nB; xgC = nC; xgD = nD;
        par ^= 1;
    }
}

// ---------------- fallback: R2 single-block kernel (no ws needed) ----------
__global__ __launch_bounds__(1024) void lstm_fused(
    const float* __restrict__ x, const float* __restrict__ Wx,
    const float* __restrict__ Wh, const float* __restrict__ bias,
    const float* __restrict__ Wout, const float* __restrict__ bout,
    float* __restrict__ out)
{
    __shared__ float h_lds[Hh];
    __shared__ float gates_lds[G4];
    __shared__ float x_lds[2][Dd];
    __shared__ float wout_t[Cc][Hh];
    __shared__ float bout_l[Cc];
    const int tid = threadIdx.x;
    const int b   = blockIdx.x;
    float wx[Dd];
    #pragma unroll
    for (int d = 0; d < Dd; ++d) wx[d] = Wx[d * G4 + tid];
    const float bj = bias[tid];
    if (tid < Hh) h_lds[tid] = 0.0f;
    for (int i = tid; i < Cc * Hh; i += 1024) wout_t[i % Cc][i / Cc] = Wout[i];
    if (tid < Cc) bout_l[tid] = bout[tid];
    const float* xB = x + (long)b * Tt * Dd;
    if (tid < Dd) x_lds[0][tid] = xB[tid];
    float c_state = 0.0f;
    __syncthreads();
    const float* WhB = Wh + tid;
    for (int t = 0; t < Tt; ++t) {
        float gg = bj;
        const float* xr = x_lds[t & 1];
        #pragma unroll
        for (int d = 0; d < Dd; ++d) gg += xr[d] * wx[d];
        #pragma unroll 8
        for (int k = 0; k < Hh; ++k) gg += h_lds[k] * WhB[k * G4];
        float a;
        if (tid < 2 * Hh)      a = 1.0f / (1.0f + expf(-gg));
        else if (tid < 3 * Hh) a = tanhf(gg);
        else                   a = 1.0f / (1.0f + expf(-gg));
        gates_lds[tid] = a;
        __syncthreads();
        if (tid < Hh) {
            float iv = gates_lds[tid], fv = gates_lds[tid + Hh];
            float gv = gates_lds[tid + 2 * Hh], ov = gates_lds[tid + 3 * Hh];
            c_state = fv * c_state + iv * gv;
            h_lds[tid] = ov * tanhf(c_state);
        } else if (tid >= 384 && tid < 448) {
            int tn = t + 1;
            if (tn < Tt) x_lds[tn & 1][tid - 384] = xB[(long)tn * Dd + (tid - 384)];
        }
        __syncthreads();
        const int w = tid >> 6, l = tid & 63;
        if (w < Cc) {
            float p = 0.0f;
            #pragma unroll
            for (int qq = 0; qq < 4; ++qq) p += h_lds[l + 64 * qq] * wout_t[w][l + 64 * qq];
            #pragma unroll
            for (int off = 32; off > 0; off >>= 1) p += __shfl_down(p, off);
            if (l == 0) out[((long)b * Tt + t) * Cc + w] = p + bout_l[w];
        }
    }
}

extern "C" void kernel_launch(void* const* d_in, const int* in_sizes, int n_in,
                              void* d_out, int out_size, void* d_ws, size_t ws_size,
                              hipStream_t stream) {
    const float* x    = (const float*)d_in[0];
    const float* Wx   = (const float*)d_in[1];
    const float* Wh   = (const float*)d_in[2];
    const float* bvec = (const float*)d_in[3];
    const float* Wout = (const float*)d_in[4];
    const float* bout = (const float*)d_in[5];
    float* outp = (float*)d_out;

    if (ws_size >= XG_BYTES) {
        unsigned short* xgws = (unsigned short*)d_ws;
        xg_gemm<<<dim3(BT / 32, 4), dim3(256), 0, stream>>>(x, Wx, bvec, xgws);
        lstm_xg<<<dim3(128), dim3(256), 0, stream>>>(xgws, Wh, Wout, bout, outp);
    } else {
        lstm_fused<<<dim3(128), dim3(1024), 0, stream>>>(x, Wx, Wh, bvec, Wout, bout, outp);
    }
}